// Round 2
// baseline (210.445 us; speedup 1.0000x reference)
//
#include <hip/hip_runtime.h>

#define KNN_EPS 1e-8f
#define C_FEAT 128
#define N_SRC 65536
#define M_QRY 262144
#define QBLK 8   // queries per 256-thread block; 32 lanes x 4 channels per query

typedef float f4 __attribute__((ext_vector_type(4)));

// Single pass: LDS-staged metadata + direct fp32 gathers.
// Phase 1: 24 threads compute idx + unnormalized w for the block's 8 queries -> LDS.
// Phase 2: 32 lanes per query, one f4 (16 B) per lane x 3 neighbors, weight, store.
__global__ __launch_bounds__(256) void knn_interp_kernel(
    const float* __restrict__ s_feats,
    const float* __restrict__ q_points,
    const float* __restrict__ s_points,
    const int*   __restrict__ nbr_idx,
    float* __restrict__ out)
{
    __shared__ int   s_i[QBLK][3];
    __shared__ float s_wt[QBLK][3];

    const int tid    = threadIdx.x;
    const int mblock = blockIdx.x * QBLK;

    // Phase 1: one (query, k) pair per thread; lanes 0..23 of wave 0 active.
    if (tid < QBLK * 3) {
        const int q = tid / 3;               // magic-mul, cheap
        const int k = tid - q * 3;
        const int m = mblock + q;
        const int s = nbr_idx[m * 3 + k];
        const float dx = q_points[m * 3 + 0] - s_points[s * 3 + 0];
        const float dy = q_points[m * 3 + 1] - s_points[s * 3 + 1];
        const float dz = q_points[m * 3 + 2] - s_points[s * 3 + 2];
        s_i[q][k]  = s;
        s_wt[q][k] = __builtin_amdgcn_rcpf(dx * dx + dy * dy + dz * dz + KNN_EPS);
    }
    __syncthreads();

    // Phase 2: group of 32 lanes per query, 4 contiguous channels per lane.
    const int q  = tid >> 5;                 // 0..7
    const int c4 = tid & 31;                 // 16 B slot within the 512 B fp32 row
    const int m  = mblock + q;

    // Broadcast LDS reads (same addr within each 32-lane group -> conflict-free).
    const float w0 = s_wt[q][0], w1 = s_wt[q][1], w2 = s_wt[q][2];
    const float inv = __builtin_amdgcn_rcpf(w0 + w1 + w2);
    const int i0 = s_i[q][0], i1 = s_i[q][1], i2 = s_i[q][2];

    // 3 gathers/thread, global_load_dwordx4: one wave covers 2 full rows/instr.
    // No nontemporal hint: rows are re-gathered ~12x on average, keep them in L2/L3.
    const f4 v0 = ((const f4*)(s_feats + (size_t)i0 * C_FEAT))[c4];
    const f4 v1 = ((const f4*)(s_feats + (size_t)i1 * C_FEAT))[c4];
    const f4 v2 = ((const f4*)(s_feats + (size_t)i2 * C_FEAT))[c4];

    const f4 r = (w0 * inv) * v0 + (w1 * inv) * v1 + (w2 * inv) * v2;
    __builtin_nontemporal_store(r, (f4*)(out + (size_t)m * C_FEAT) + c4);
}

extern "C" void kernel_launch(void* const* d_in, const int* in_sizes, int n_in,
                              void* d_out, int out_size, void* d_ws, size_t ws_size,
                              hipStream_t stream) {
    const float* s_feats  = (const float*)d_in[0];
    const float* q_points = (const float*)d_in[1];
    const float* s_points = (const float*)d_in[2];
    const int*   nbr_idx  = (const int*)d_in[3];
    float* out = (float*)d_out;
    (void)d_ws; (void)ws_size;               // workspace unused: no fp16 table pass

    const int grid = M_QRY / QBLK;           // 32768 blocks
    knn_interp_kernel<<<grid, 256, 0, stream>>>(s_feats, q_points, s_points,
                                               nbr_idx, out);
}

// Round 3
// 194.103 us; speedup vs baseline: 1.0842x; 1.0842x over previous
//
#include <hip/hip_runtime.h>

#define KNN_EPS 1e-8f
#define C_FEAT 128
#define N_SRC 65536
#define M_QRY 262144
#define QBLK 16   // queries per 256-thread block; 16 lanes x 8 channels per query

typedef float    f4 __attribute__((ext_vector_type(4)));
typedef float    f8 __attribute__((ext_vector_type(8)));
typedef _Float16 h4 __attribute__((ext_vector_type(4)));
typedef _Float16 h8 __attribute__((ext_vector_type(8)));

// Pass 1: fp32 -> fp16 table in workspace. 16 B loads AND 16 B stores per lane.
// 50 MB total traffic; target ~8 us at the 6.3 TB/s streaming ceiling.
__global__ __launch_bounds__(256) void cvt_feats_kernel(
    const float* __restrict__ s_feats, _Float16* __restrict__ ws)
{
    const int t = blockIdx.x * blockDim.x + threadIdx.x;   // [0, N_SRC*C_FEAT/8)
    const f4 a = ((const f4*)s_feats)[2 * t + 0];
    const f4 b = ((const f4*)s_feats)[2 * t + 1];
    h8 h;
    h.lo = __builtin_convertvector(a, h4);
    h.hi = __builtin_convertvector(b, h4);
    // Plain (cacheable) store: table lines stay resident in L2/L3 for the
    // gather pass; kernel-boundary writeback leaves them in L3.
    ((h8*)ws)[t] = h;
}

// Pass 2: LDS-staged metadata + wide fp16 gathers. (Round-1 structure: 25 us,
// at the 128 MB write floor + compulsory table fetch.)
__global__ __launch_bounds__(256) void knn_interp_kernel(
    const _Float16* __restrict__ feats16,
    const float* __restrict__ q_points,
    const float* __restrict__ s_points,
    const int*   __restrict__ nbr_idx,
    float* __restrict__ out)
{
    __shared__ int   s_i[QBLK][3];
    __shared__ float s_wt[QBLK][3];

    const int tid    = threadIdx.x;
    const int mblock = blockIdx.x * QBLK;

    // Phase 1: one (query, k) pair per thread; lanes 0..47 of wave 0 active.
    if (tid < QBLK * 3) {
        const int q = tid / 3;
        const int k = tid - q * 3;
        const int m = mblock + q;
        const int s = nbr_idx[m * 3 + k];
        const float dx = q_points[m * 3 + 0] - s_points[s * 3 + 0];
        const float dy = q_points[m * 3 + 1] - s_points[s * 3 + 1];
        const float dz = q_points[m * 3 + 2] - s_points[s * 3 + 2];
        s_i[q][k]  = s;
        s_wt[q][k] = __builtin_amdgcn_rcpf(dx * dx + dy * dy + dz * dz + KNN_EPS);
    }
    __syncthreads();

    // Phase 2: group of 16 lanes per query, 8 contiguous channels per lane.
    const int q = tid >> 4;                  // 0..15
    const int l = tid & 15;                  // 16 B slot within the 256 B fp16 row
    const int m = mblock + q;

    // Broadcast LDS reads (same addr within a 16-lane group -> conflict-free).
    const float w0 = s_wt[q][0], w1 = s_wt[q][1], w2 = s_wt[q][2];
    const float inv = __builtin_amdgcn_rcpf(w0 + w1 + w2);
    const int i0 = s_i[q][0], i1 = s_i[q][1], i2 = s_i[q][2];

    // 3 gathers/thread, global_load_dwordx4 each: one wave covers 4 rows/instr.
    const h8 v0 = ((const h8*)(feats16 + (size_t)i0 * C_FEAT))[l];
    const h8 v1 = ((const h8*)(feats16 + (size_t)i1 * C_FEAT))[l];
    const h8 v2 = ((const h8*)(feats16 + (size_t)i2 * C_FEAT))[l];

    const f8 r = (w0 * inv) * __builtin_convertvector(v0, f8)
               + (w1 * inv) * __builtin_convertvector(v1, f8)
               + (w2 * inv) * __builtin_convertvector(v2, f8);

    float* o = out + (size_t)m * C_FEAT + l * 8;
    __builtin_nontemporal_store(__builtin_shufflevector(r, r, 0, 1, 2, 3), (f4*)o);
    __builtin_nontemporal_store(__builtin_shufflevector(r, r, 4, 5, 6, 7), (f4*)(o + 4));
}

extern "C" void kernel_launch(void* const* d_in, const int* in_sizes, int n_in,
                              void* d_out, int out_size, void* d_ws, size_t ws_size,
                              hipStream_t stream) {
    const float* s_feats  = (const float*)d_in[0];
    const float* q_points = (const float*)d_in[1];
    const float* s_points = (const float*)d_in[2];
    const int*   nbr_idx  = (const int*)d_in[3];
    float* out = (float*)d_out;
    _Float16* feats16 = (_Float16*)d_ws;   // 16 MB of ws; fully rewritten each call

    // Pass 1: convert table to fp16 (16 B/lane both directions).
    {
        const int total = N_SRC * C_FEAT / 8;       // 1,048,576 h8 groups
        cvt_feats_kernel<<<total / 256, 256, 0, stream>>>(s_feats, feats16);
    }

    // Pass 2: gather + interpolate. 16 queries per block.
    {
        const int grid = M_QRY / QBLK;              // 16384 blocks
        knn_interp_kernel<<<grid, 256, 0, stream>>>(feats16, q_points, s_points,
                                                    nbr_idx, out);
    }
}